// Round 13
// baseline (296.448 us; speedup 1.0000x reference)
//
#include <hip/hip_runtime.h>
#include <hip/hip_bf16.h>

typedef __attribute__((ext_vector_type(8))) short short8;
typedef __attribute__((ext_vector_type(4))) float f32x4;
typedef __attribute__((ext_vector_type(4))) unsigned short ushort4v;

#define MFMA16(a,b,c) __builtin_amdgcn_mfma_f32_16x16x32_bf16((a),(b),(c),0,0,0)

constexpr int BHn = 32;     // B*NH
constexpr int Tn  = 2048;
constexpr int Nn  = 512;
constexpr int Dn  = 128;
constexpr int CHn = 128;    // chunk length
constexpr int NCH = Tn / CHn;   // 16

static __device__ __forceinline__ unsigned short f2b(float x){
  __hip_bfloat16 h = __float2bfloat16(x);
  return *reinterpret_cast<unsigned short*>(&h);
}
static __device__ __forceinline__ float b2f(unsigned short u){
  unsigned v = (unsigned)u << 16;
  float f;
  __builtin_memcpy(&f, &v, 4);
  return f;
}

// ---------------- Kernel 1: RoPE(Q) -> bf16 row-major QR ----------------
__global__ __launch_bounds__(256) void rope_k(const float* __restrict__ Q,
                                              const float* __restrict__ freqs,
                                              unsigned short* __restrict__ QR){
  int gid = blockIdx.x * 256 + threadIdx.x;
  int np  = gid & 255;
  int t   = gid >> 8;
  float tf = (float)t;
  float f1 = freqs[np], f2 = freqs[np + 256];
  float s1, c1, s2, c2;
  sincosf(tf * f1, &s1, &c1);
  sincosf(tf * f2, &s2, &c2);
  size_t off = (size_t)t * Nn + np;
  for (int bh = 0; bh < BHn; ++bh){
    size_t base = (size_t)bh * Tn * Nn + off;
    float q1 = Q[base], q2 = Q[base + 256];
    QR[base]       = f2b(q1 * c1 - q2 * s1);
    QR[base + 256] = f2b(q2 * c2 + q1 * s2);
  }
}

// ---------------- fragment loaders ----------------
__device__ __forceinline__ short8 ldfrag(const unsigned short* buf, int rowbase, int k0, int ld, int lane){
  int row = rowbase + (lane & 15);
  int col = (k0 + ((lane >> 4) << 3)) ^ ((row & 7) << 3);
  return *reinterpret_cast<const short8*>(buf + row * ld + col);
}
__device__ __forceinline__ short8 gfrag(const unsigned short* Qc, int rowbase, int k0, int lane){
  return *reinterpret_cast<const short8*>(
      Qc + (size_t)(rowbase + (lane & 15)) * Nn + k0 + ((lane >> 4) << 3));
}
__device__ __forceinline__ void stage_Rs(unsigned short* Rs, uint4 a, uint4 b, int dt, int n0){
  *reinterpret_cast<uint4*>(&Rs[ dt      * 512 + (n0 ^ (( dt      & 7) << 3))]) = a;
  *reinterpret_cast<uint4*>(&Rs[(dt + 1) * 512 + (n0 ^ (((dt + 1) & 7) << 3))]) = b;
}

// ---------------- Kernel 2 (parallel): diag 64-triangles of P~ -> [128][128] image -------
__global__ __launch_bounds__(256) void pt_k(const unsigned short* __restrict__ QR,
                                            const float* __restrict__ gammap,
                                            unsigned short* __restrict__ Pt){
  __shared__ __align__(16) unsigned short Rs[64 * 512];
  __shared__ float gpow[129];
  const int tid = threadIdx.x, w = tid >> 6, lane = tid & 63;
  const int bh = blockIdx.x & 31, cc = (blockIdx.x >> 5) & 15, sub = blockIdx.x >> 9;
  const int ro = sub * 64;
  if (tid < 129) gpow[tid] = powf(gammap[0], (float)tid);
  const unsigned short* Qc = QR + (size_t)bh * Tn * Nn + (size_t)(cc * CHn + ro) * Nn;
  #pragma unroll
  for (int i = 0; i < 8; ++i){
    int p  = tid + i * 256;
    int dt = (p >> 6) << 1, n0 = (p & 63) << 3;
    const unsigned short* src = Qc + (size_t)dt * Nn + n0;
    uint4 a = *reinterpret_cast<const uint4*>(src);
    uint4 b = *reinterpret_cast<const uint4*>(src + Nn);
    stage_Rs(Rs, a, b, dt, n0);
  }
  __syncthreads();
  f32x4 p0 = {0.f,0.f,0.f,0.f}, p1 = p0, p2 = p0;
  for (int kb = 0; kb < 16; ++kb){
    int k0 = kb * 32;
    if (w == 0){
      short8 f0 = ldfrag(Rs,  0, k0, 512, lane);
      short8 f1 = ldfrag(Rs, 16, k0, 512, lane);
      p0 = MFMA16(f0, f0, p0);
      p1 = MFMA16(f1, f0, p1);
      p2 = MFMA16(f1, f1, p2);
    } else if (w == 1){
      short8 f0 = ldfrag(Rs,  0, k0, 512, lane);
      short8 f1 = ldfrag(Rs, 16, k0, 512, lane);
      short8 f2 = ldfrag(Rs, 32, k0, 512, lane);
      p0 = MFMA16(f2, f0, p0);
      p1 = MFMA16(f2, f1, p1);
      p2 = MFMA16(f2, f2, p2);
    } else if (w == 2){
      short8 f0 = ldfrag(Rs,  0, k0, 512, lane);
      short8 f1 = ldfrag(Rs, 16, k0, 512, lane);
      short8 f3 = ldfrag(Rs, 48, k0, 512, lane);
      p0 = MFMA16(f3, f0, p0);
      p1 = MFMA16(f3, f1, p1);
    } else {
      short8 f2 = ldfrag(Rs, 32, k0, 512, lane);
      short8 f3 = ldfrag(Rs, 48, k0, 512, lane);
      p0 = MFMA16(f3, f2, p0);
      p1 = MFMA16(f3, f3, p1);
    }
  }
  unsigned short* Pq = Pt + (size_t)(bh * NCH + cc) * (CHn * CHn);
  auto pwrite = [&](f32x4 pa, int tI, int tJ){
    int j  = tJ * 16 + (lane & 15);
    int i0 = tI * 16 + ((lane >> 4) << 2);
    #pragma unroll
    for (int r = 0; r < 4; ++r){
      int i = i0 + r;
      float v = (j < i) ? pa[r] * gpow[i + ro] : 0.f;
      Pq[(i + ro) * CHn + ro + (j ^ ((i & 7) << 3))] = f2b(v);
    }
  };
  if      (w == 0){ pwrite(p0,0,0); pwrite(p1,1,0); pwrite(p2,1,1); pwrite(p0,0,1); }
  else if (w == 1){ pwrite(p0,2,0); pwrite(p1,2,1); pwrite(p2,2,2); pwrite(p0,0,2); }
  else if (w == 2){ pwrite(p0,3,0); pwrite(p1,3,1); pwrite(p0,0,3); pwrite(p1,1,2); }
  else            { pwrite(p0,3,2); pwrite(p1,3,3); pwrite(p0,1,3); pwrite(p1,2,3); }
}

// ---------------- Kernel 3 (parallel): off-diag 64x64 block of P~ ------------------------
__global__ __launch_bounds__(256) void po_k(const unsigned short* __restrict__ QR,
                                            const float* __restrict__ gammap,
                                            unsigned short* __restrict__ Pt){
  __shared__ float gpow[129];
  const int tid = threadIdx.x, w = tid >> 6, lane = tid & 63;
  const int bh = blockIdx.x & 31, cc = blockIdx.x >> 5;
  if (tid < 129) gpow[tid] = powf(gammap[0], (float)tid);
  __syncthreads();
  const unsigned short* QB = QR + (size_t)bh * Tn * Nn + (size_t)(cc * CHn) * Nn;
  const unsigned short* QA = QB + (size_t)64 * Nn;
  f32x4 acc[4] = {{0.f,0.f,0.f,0.f},{0.f,0.f,0.f,0.f},{0.f,0.f,0.f,0.f},{0.f,0.f,0.f,0.f}};
  for (int kb = 0; kb < 16; ++kb){
    int k0 = kb * 32;
    short8 fa = gfrag(QA, w * 16, k0, lane);
    #pragma unroll
    for (int t = 0; t < 4; ++t){
      short8 fb = gfrag(QB, t * 16, k0, lane);
      acc[t] = MFMA16(fa, fb, acc[t]);
    }
  }
  unsigned short* Pq = Pt + (size_t)(bh * NCH + cc) * (CHn * CHn);
  #pragma unroll
  for (int t = 0; t < 4; ++t){
    int j  = t * 16 + (lane & 15);
    int i0 = w * 16 + ((lane >> 4) << 2);
    #pragma unroll
    for (int r = 0; r < 4; ++r){
      int i = i0 + r;
      float v = acc[t][r] * gpow[64 + i];
      Pq[(64 + i) * CHn + (j ^ ((i & 7) << 3))] = f2b(v);
    }
  }
}

// ---------------- Kernel 4 (parallel): U_c = Sum_dt gamma^-dt R (x) V -> bf16 [n][d] -----
// grid 4096 = bh + 32*cc + 512*dch; block 512 (8 waves, 4 n-tiles each).
// State-update code lifted verbatim from the round-12 scan (st init = 0).
__global__ __launch_bounds__(512) void u_k(const unsigned short* __restrict__ QR,
                                           const float* __restrict__ V,
                                           const float* __restrict__ gammap,
                                           unsigned short* __restrict__ U){
  __shared__ __align__(16) unsigned short VTs[16 * 128];
  __shared__ float gpinv[129];
  const int tid = threadIdx.x, w = tid >> 6, lane = tid & 63;
  const int bh = blockIdx.x & 31, cc = (blockIdx.x >> 5) & 15, dch = blockIdx.x >> 9;
  const int d0 = dch * 16;
  if (tid < 129) gpinv[tid] = powf(gammap[0], -(float)tid);
  __syncthreads();
  {
    int dtv = tid >> 2, dp0 = (tid & 3) << 2;
    f32x4 v4 = *reinterpret_cast<const f32x4*>(
        V + ((size_t)bh * Tn + cc * CHn + dtv) * Dn + d0 + dp0);
    float sc = gpinv[dtv];
    #pragma unroll
    for (int r = 0; r < 4; ++r){
      int d = dp0 + r;
      VTs[d * 128 + (dtv ^ ((d & 7) << 3))] = f2b(v4[r] * sc);
    }
  }
  __syncthreads();
  const unsigned short* Qc = QR + (size_t)bh * Tn * Nn + (size_t)(cc * CHn) * Nn;
  const int sb = w * 4;
  f32x4 st[4] = {{0.f,0.f,0.f,0.f},{0.f,0.f,0.f,0.f},{0.f,0.f,0.f,0.f},{0.f,0.f,0.f,0.f}};
  #pragma unroll
  for (int ks = 0; ks < 4; ++ks){
    short8 av = ldfrag(VTs, 0, ks * 32, 128, lane);
    #pragma unroll
    for (int j = 0; j < 4; ++j){
      int n = (sb + j) * 16 + (lane & 15);
      const unsigned short* col = Qc + (size_t)(ks * 32 + ((lane >> 4) << 3)) * Nn + n;
      short8 bn;
      #pragma unroll
      for (int e = 0; e < 8; ++e) bn[e] = (short)col[(size_t)e * Nn];
      st[j] = MFMA16(av, bn, st[j]);
    }
  }
  unsigned short* Uc = U + (size_t)(bh * NCH + cc) * Nn * Dn;
  #pragma unroll
  for (int j = 0; j < 4; ++j){
    int n = (sb + j) * 16 + (lane & 15);
    ushort4v o;
    #pragma unroll
    for (int r = 0; r < 4; ++r) o[r] = f2b(st[j][r]);
    *reinterpret_cast<ushort4v*>(Uc + (size_t)n * Dn + d0 + ((lane >> 4) << 2)) = o;
  }
}

// ---------------- Kernel 5: slim scan — out chains + elementwise state from U ------------
// All 8 waves: out i-tile w (inter chain + intra via Pt) + 4 state tiles each (U add).
__global__ __launch_bounds__(512, 1) void lattn_s(
    const unsigned short* __restrict__ QR,
    const unsigned short* __restrict__ Pt,
    const unsigned short* __restrict__ U,
    const float* __restrict__ V,
    const float* __restrict__ S_prev,
    const float* __restrict__ gammap,
    float* __restrict__ Out,
    float* __restrict__ Sfin)
{
  __shared__ __align__(16) unsigned short SbTs[16 * 512];
  __shared__ __align__(16) unsigned short VTs[2][16 * 128];
  __shared__ float gpow[129], gpinv[129];

  const int tid  = threadIdx.x;
  const int w    = tid >> 6;
  const int lane = tid & 63;
  const int bh   = blockIdx.x & 31;
  const int dch  = blockIdx.x >> 5;
  const int d0   = dch * 16;
  const float g  = gammap[0];

  const unsigned short* QRbh = QR + (size_t)bh * Tn * Nn;
  const unsigned short* Ptbh = Pt + (size_t)bh * NCH * (CHn * CHn);
  const unsigned short* Ubh  = U  + (size_t)bh * NCH * Nn * Dn;
  const float* Vbh = V + (size_t)bh * Tn * Dn;

  if (tid < 129){
    gpow[tid]  = powf(g,  (float)tid);
    gpinv[tid] = powf(g, -(float)tid);
  }

  const int sb = w * 4;    // 4 state tiles per wave
  f32x4 st[4];
  #pragma unroll
  for (int j = 0; j < 4; ++j){
    int n = (sb + j) * 16 + (lane & 15);
    st[j] = *reinterpret_cast<const f32x4*>(
        S_prev + (size_t)bh * Nn * Dn + (size_t)n * Dn + d0 + ((lane >> 4) << 2));
  }
  __syncthreads();
  const float g128 = gpow[128];

  // stage SbTs (S_start of chunk 0) + VT[0]
  #pragma unroll
  for (int j = 0; j < 4; ++j){
    int n  = (sb + j) * 16 + (lane & 15);
    int dl = (lane >> 4) << 2;
    #pragma unroll
    for (int r = 0; r < 4; ++r){
      int d = dl + r;
      SbTs[d * 512 + (n ^ ((d & 7) << 3))] = f2b(st[j][r]);
    }
  }
  {
    int dtv = tid >> 2, dp0 = (tid & 3) << 2;
    f32x4 v4 = *reinterpret_cast<const f32x4*>(Vbh + (size_t)dtv * Dn + d0 + dp0);
    float sc = gpinv[dtv];
    #pragma unroll
    for (int r = 0; r < 4; ++r){
      int d = dp0 + r;
      VTs[0][d * 128 + (dtv ^ ((d & 7) << 3))] = f2b(v4[r] * sc);
    }
  }
  __syncthreads();

  for (int c = 0; c < NCH; ++c){
    const int t0 = c * CHn;
    const int vb = c & 1;
    const bool pf = (c + 1 < NCH);
    const unsigned short* Qc = QRbh + (size_t)t0 * Nn;

    f32x4 va4 = {0.f, 0.f, 0.f, 0.f};
    const int dtv_ = tid >> 2, dp0_ = (tid & 3) << 2;
    if (pf)
      va4 = *reinterpret_cast<const f32x4*>(Vbh + (size_t)(t0 + CHn + dtv_) * Dn + d0 + dp0_);

    // ================= Ph1: out i-tile w =================
    {
      f32x4 o = {0.f, 0.f, 0.f, 0.f};
      for (int kb = 0; kb < 16; ++kb){
        int k0 = kb * 32;
        short8 fs = ldfrag(SbTs, 0, k0, 512, lane);
        short8 fi = gfrag(Qc, w * 16, k0, lane);
        o = MFMA16(fs, fi, o);
      }
      float gi = gpow[w * 16 + (lane & 15)];
      #pragma unroll
      for (int r = 0; r < 4; ++r) o[r] *= gi;
      const unsigned short* Pq = Ptbh + (size_t)c * (CHn * CHn);
      const int nks = (w >> 1) + 1;   // rows [w*16, w*16+16): j < (w+1)*16
      #pragma unroll
      for (int ks = 0; ks < 4; ++ks) if (ks < nks){
        short8 av = ldfrag(VTs[vb], 0, ks * 32, 128, lane);
        short8 bp = ldfrag(Pq, w * 16, ks * 32, CHn, lane);
        o = MFMA16(av, bp, o);
      }
      int ti = t0 + w * 16 + (lane & 15);
      *reinterpret_cast<f32x4*>(
          Out + (size_t)bh * Tn * Dn + (size_t)ti * Dn + d0 + ((lane >> 4) << 2)) = o;
    }
    // state: S = gamma^CH * (S + U_c)  (elementwise, U precomputed)
    {
      const unsigned short* Uc = Ubh + (size_t)c * Nn * Dn;
      #pragma unroll
      for (int j = 0; j < 4; ++j){
        int n = (sb + j) * 16 + (lane & 15);
        ushort4v u4 = *reinterpret_cast<const ushort4v*>(
            Uc + (size_t)n * Dn + d0 + ((lane >> 4) << 2));
        #pragma unroll
        for (int r = 0; r < 4; ++r) st[j][r] = (st[j][r] + b2f(u4[r])) * g128;
      }
    }
    __syncthreads();

    // ================= Ph2: SbT(c+1) + VT(c+1) =================
    #pragma unroll
    for (int j = 0; j < 4; ++j){
      int n  = (sb + j) * 16 + (lane & 15);
      int dl = (lane >> 4) << 2;
      #pragma unroll
      for (int r = 0; r < 4; ++r){
        int d = dl + r;
        SbTs[d * 512 + (n ^ ((d & 7) << 3))] = f2b(st[j][r]);
      }
    }
    if (pf){
      float sc = gpinv[dtv_];
      #pragma unroll
      for (int r = 0; r < 4; ++r){
        int d = dp0_ + r;
        VTs[vb ^ 1][d * 128 + (dtv_ ^ ((d & 7) << 3))] = f2b(va4[r] * sc);
      }
    }
    __syncthreads();
  }

  // ---- epilogue: final state ----
  #pragma unroll
  for (int j = 0; j < 4; ++j){
    int n = (sb + j) * 16 + (lane & 15);
    *reinterpret_cast<f32x4*>(
        Sfin + (size_t)bh * Nn * Dn + (size_t)n * Dn + d0 + ((lane >> 4) << 2)) = st[j];
  }
}

// ---------------- Kernel 4-fallback: round-12 scan (state update in-loop) ----------------
__global__ __launch_bounds__(512, 1) void lattn_main(
    const unsigned short* __restrict__ QR,
    const unsigned short* __restrict__ Pt,
    const float* __restrict__ V,
    const float* __restrict__ S_prev,
    const float* __restrict__ gammap,
    float* __restrict__ Out,
    float* __restrict__ Sfin)
{
  __shared__ __align__(16) unsigned short SbTs[16 * 512];
  __shared__ __align__(16) unsigned short VTs[2][16 * 128];
  __shared__ float gpow[129], gpinv[129];

  const int tid  = threadIdx.x;
  const int w    = tid >> 6;
  const int lane = tid & 63;
  const int bh   = blockIdx.x & 31;
  const int dch  = blockIdx.x >> 5;
  const int d0   = dch * 16;
  const float g  = gammap[0];

  const unsigned short* QRbh = QR + (size_t)bh * Tn * Nn;
  const unsigned short* Ptbh = Pt + (size_t)bh * NCH * (CHn * CHn);
  const float* Vbh = V + (size_t)bh * Tn * Dn;

  if (tid < 129){
    gpow[tid]  = powf(g,  (float)tid);
    gpinv[tid] = powf(g, -(float)tid);
  }

  const int snt = (w < 4) ? 2 : 6;
  const int sb  = (w < 4) ? w * 2 : 8 + (w - 4) * 6;
  f32x4 st[6];
  #pragma unroll
  for (int j = 0; j < 6; ++j) if (j < snt){
    int n = (sb + j) * 16 + (lane & 15);
    st[j] = *reinterpret_cast<const f32x4*>(
        S_prev + (size_t)bh * Nn * Dn + (size_t)n * Dn + d0 + ((lane >> 4) << 2));
  }
  __syncthreads();
  const float g128 = gpow[128];

  #pragma unroll
  for (int j = 0; j < 6; ++j) if (j < snt){
    int n  = (sb + j) * 16 + (lane & 15);
    int dl = (lane >> 4) << 2;
    #pragma unroll
    for (int r = 0; r < 4; ++r){
      int d = dl + r;
      SbTs[d * 512 + (n ^ ((d & 7) << 3))] = f2b(st[j][r]);
    }
  }
  {
    int dtv = tid >> 2, dp0 = (tid & 3) << 2;
    f32x4 v4 = *reinterpret_cast<const f32x4*>(Vbh + (size_t)dtv * Dn + d0 + dp0);
    float sc = gpinv[dtv];
    #pragma unroll
    for (int r = 0; r < 4; ++r){
      int d = dp0 + r;
      VTs[0][d * 128 + (dtv ^ ((d & 7) << 3))] = f2b(v4[r] * sc);
    }
  }
  __syncthreads();

  for (int c = 0; c < NCH; ++c){
    const int t0 = c * CHn;
    const int vb = c & 1;
    const bool pf = (c + 1 < NCH);
    const unsigned short* Qc = QRbh + (size_t)t0 * Nn;

    f32x4 va4 = {0.f, 0.f, 0.f, 0.f};
    const int dtv_ = tid >> 2, dp0_ = (tid & 3) << 2;
    if (pf)
      va4 = *reinterpret_cast<const f32x4*>(Vbh + (size_t)(t0 + CHn + dtv_) * Dn + d0 + dp0_);

    if (w < 4){
      const int it0 = w, it1 = w + 4;
      f32x4 o0 = {0.f,0.f,0.f,0.f}, o1 = o0;
      for (int kb = 0; kb < 16; ++kb){
        int k0 = kb * 32;
        short8 fs = ldfrag(SbTs, 0, k0, 512, lane);
        short8 fa = gfrag(Qc, it0 * 16, k0, lane);
        short8 fb = gfrag(Qc, it1 * 16, k0, lane);
        o0 = MFMA16(fs, fa, o0);
        o1 = MFMA16(fs, fb, o1);
      }
      float g0 = gpow[it0 * 16 + (lane & 15)];
      float g1 = gpow[it1 * 16 + (lane & 15)];
      #pragma unroll
      for (int r = 0; r < 4; ++r){ o0[r] *= g0; o1[r] *= g1; }
      const unsigned short* Pq = Ptbh + (size_t)c * (CHn * CHn);
      #pragma unroll
      for (int ks = 0; ks < 4; ++ks){
        short8 av = ldfrag(VTs[vb], 0, ks * 32, 128, lane);
        if (ks < 2){
          short8 b0 = ldfrag(Pq, it0 * 16, ks * 32, CHn, lane);
          o0 = MFMA16(av, b0, o0);
        }
        short8 b1 = ldfrag(Pq, it1 * 16, ks * 32, CHn, lane);
        o1 = MFMA16(av, b1, o1);
      }
      int ti0 = t0 + it0 * 16 + (lane & 15);
      int ti1 = t0 + it1 * 16 + (lane & 15);
      *reinterpret_cast<f32x4*>(
          Out + (size_t)bh * Tn * Dn + (size_t)ti0 * Dn + d0 + ((lane >> 4) << 2)) = o0;
      *reinterpret_cast<f32x4*>(
          Out + (size_t)bh * Tn * Dn + (size_t)ti1 * Dn + d0 + ((lane >> 4) << 2)) = o1;
    }
    #pragma unroll
    for (int ks = 0; ks < 4; ++ks){
      short8 av = ldfrag(VTs[vb], 0, ks * 32, 128, lane);
      #pragma unroll
      for (int j = 0; j < 6; ++j) if (j < snt){
        int n = (sb + j) * 16 + (lane & 15);
        const unsigned short* col = Qc + (size_t)(ks * 32 + ((lane >> 4) << 3)) * Nn + n;
        short8 bn;
        #pragma unroll
        for (int e = 0; e < 8; ++e) bn[e] = (short)col[(size_t)e * Nn];
        st[j] = MFMA16(av, bn, st[j]);
      }
    }
    #pragma unroll
    for (int j = 0; j < 6; ++j) if (j < snt)
      #pragma unroll
      for (int r = 0; r < 4; ++r) st[j][r] *= g128;
    __syncthreads();

    #pragma unroll
    for (int j = 0; j < 6; ++j) if (j < snt){
      int n  = (sb + j) * 16 + (lane & 15);
      int dl = (lane >> 4) << 2;
      #pragma unroll
      for (int r = 0; r < 4; ++r){
        int d = dl + r;
        SbTs[d * 512 + (n ^ ((d & 7) << 3))] = f2b(st[j][r]);
      }
    }
    if (pf){
      float sc = gpinv[dtv_];
      #pragma unroll
      for (int r = 0; r < 4; ++r){
        int d = dp0_ + r;
        VTs[vb ^ 1][d * 128 + (dtv_ ^ ((d & 7) << 3))] = f2b(va4[r] * sc);
      }
    }
    __syncthreads();
  }

  #pragma unroll
  for (int j = 0; j < 6; ++j) if (j < snt){
    int n = (sb + j) * 16 + (lane & 15);
    *reinterpret_cast<f32x4*>(
        Sfin + (size_t)bh * Nn * Dn + (size_t)n * Dn + d0 + ((lane >> 4) << 2)) = st[j];
  }
}

extern "C" void kernel_launch(void* const* d_in, const int* in_sizes, int n_in,
                              void* d_out, int out_size, void* d_ws, size_t ws_size,
                              hipStream_t stream){
  const float* Q      = (const float*)d_in[0];
  const float* V      = (const float*)d_in[1];
  const float* S_prev = (const float*)d_in[2];
  const float* freqs  = (const float*)d_in[3];
  const float* gamma  = (const float*)d_in[4];
  float* Out  = (float*)d_out;
  float* Sfin = Out + (size_t)BHn * Tn * Dn;

  const size_t QRs = (size_t)BHn * Tn * Nn;            // 33.5M shorts (64 MiB)
  const size_t Pts = (size_t)BHn * NCH * CHn * CHn;    //  8.4M shorts (16 MiB)
  const size_t Us  = (size_t)BHn * NCH * Nn * Dn;      // 33.5M shorts (64 MiB)
  unsigned short* QR = (unsigned short*)d_ws;
  unsigned short* Pt = QR + QRs;
  unsigned short* U  = Pt + Pts;

  rope_k<<<2048, 256, 0, stream>>>(Q, freqs, QR);
  pt_k<<<1024, 256, 0, stream>>>(QR, gamma, Pt);
  po_k<<<512, 256, 0, stream>>>(QR, gamma, Pt);
  if (ws_size >= 2 * (QRs + Pts + Us)){
    u_k<<<4096, 512, 0, stream>>>(QR, V, gamma, U);
    lattn_s<<<256, 512, 0, stream>>>(QR, Pt, U, V, S_prev, gamma, Out, Sfin);
  } else {
    lattn_main<<<256, 512, 0, stream>>>(QR, Pt, V, S_prev, gamma, Out, Sfin);
  }
}

// Round 14
// 216.934 us; speedup vs baseline: 1.3665x; 1.3665x over previous
//
#include <hip/hip_runtime.h>
#include <hip/hip_bf16.h>

typedef __attribute__((ext_vector_type(8))) short short8;
typedef __attribute__((ext_vector_type(4))) float f32x4;

#define MFMA16(a,b,c) __builtin_amdgcn_mfma_f32_16x16x32_bf16((a),(b),(c),0,0,0)

constexpr int BHn = 32;     // B*NH
constexpr int Tn  = 2048;
constexpr int Nn  = 512;
constexpr int Dn  = 128;
constexpr int CHn = 128;    // chunk length
constexpr int NCH = Tn / CHn;   // 16

static __device__ __forceinline__ unsigned short f2b(float x){
  __hip_bfloat16 h = __float2bfloat16(x);
  return *reinterpret_cast<unsigned short*>(&h);
}

// ---------------- Kernel 1: RoPE(Q) -> bf16 row-major QR ----------------
__global__ __launch_bounds__(256) void rope_k(const float* __restrict__ Q,
                                              const float* __restrict__ freqs,
                                              unsigned short* __restrict__ QR){
  int gid = blockIdx.x * 256 + threadIdx.x;
  int np  = gid & 255;
  int t   = gid >> 8;
  float tf = (float)t;
  float f1 = freqs[np], f2 = freqs[np + 256];
  float s1, c1, s2, c2;
  sincosf(tf * f1, &s1, &c1);
  sincosf(tf * f2, &s2, &c2);
  size_t off = (size_t)t * Nn + np;
  for (int bh = 0; bh < BHn; ++bh){
    size_t base = (size_t)bh * Tn * Nn + off;
    float q1 = Q[base], q2 = Q[base + 256];
    QR[base]       = f2b(q1 * c1 - q2 * s1);
    QR[base + 256] = f2b(q2 * c2 + q1 * s2);
  }
}

// ---------------- fragment loaders ----------------
// swizzled loader (LDS or global swizzled image): col ^= (row&7)<<3 (bits 3-5 only)
__device__ __forceinline__ short8 ldfrag(const unsigned short* buf, int rowbase, int k0, int ld, int lane){
  int row = rowbase + (lane & 15);
  int col = (k0 + ((lane >> 4) << 3)) ^ ((row & 7) << 3);
  return *reinterpret_cast<const short8*>(buf + row * ld + col);
}
// global row-major frag: lane reads R[rowbase+(lane&15)][k0+(lane>>4)*8 ..+8]
__device__ __forceinline__ short8 gfrag(const unsigned short* Qc, int rowbase, int k0, int lane){
  return *reinterpret_cast<const short8*>(
      Qc + (size_t)(rowbase + (lane & 15)) * Nn + k0 + ((lane >> 4) << 3));
}

// ---------------- Kernel 2 (parallel, stage-free): full lower-tri P~ image ----------------
// grid 512 = bh + 32*cc; block 256 (4 waves). Wave w computes two ti row-groups:
// w0:{0,7} w1:{1,6} w2:{2,5} w3:{3,4} -> 9 product tiles each, + 3 zero tiles.
// All frags direct from global QR rows (L2-hot chunk); no LDS staging, no extra barrier.
__global__ __launch_bounds__(256) void pd_k(const unsigned short* __restrict__ QR,
                                            const float* __restrict__ gammap,
                                            unsigned short* __restrict__ Pt){
  __shared__ float gpow[129];
  const int tid = threadIdx.x, w = tid >> 6, lane = tid & 63;
  const int bh = blockIdx.x & 31, cc = blockIdx.x >> 5;
  if (tid < 129) gpow[tid] = powf(gammap[0], (float)tid);
  __syncthreads();
  const unsigned short* Qc = QR + (size_t)bh * Tn * Nn + (size_t)(cc * CHn) * Nn;

  int tiA, ntA, tiB, ntB;
  if      (w == 0){ tiA = 0; ntA = 1; tiB = 7; ntB = 8; }
  else if (w == 1){ tiA = 1; ntA = 2; tiB = 6; ntB = 7; }
  else if (w == 2){ tiA = 2; ntA = 3; tiB = 5; ntB = 6; }
  else            { tiA = 3; ntA = 4; tiB = 4; ntB = 5; }

  f32x4 accA[4], accB[8];
  #pragma unroll
  for (int t = 0; t < 4; ++t) accA[t] = {0.f, 0.f, 0.f, 0.f};
  #pragma unroll
  for (int t = 0; t < 8; ++t) accB[t] = {0.f, 0.f, 0.f, 0.f};

  for (int kb = 0; kb < 16; ++kb){
    int k0 = kb * 32;
    short8 faA = gfrag(Qc, tiA * 16, k0, lane);
    short8 faB = gfrag(Qc, tiB * 16, k0, lane);
    #pragma unroll
    for (int tj = 0; tj < 8; ++tj){
      short8 fb = gfrag(Qc, tj * 16, k0, lane);
      if (tj < ntA) accA[tj] = MFMA16(faA, fb, accA[tj]);
      if (tj < ntB) accB[tj] = MFMA16(faB, fb, accB[tj]);
    }
  }

  unsigned short* Pq = Pt + (size_t)(bh * NCH + cc) * (CHn * CHn);
  auto pw = [&](f32x4 pa, int ti, int tj, bool diag){
    int jg = tj * 16 + (lane & 15);
    int i0 = ti * 16 + ((lane >> 4) << 2);
    #pragma unroll
    for (int r = 0; r < 4; ++r){
      int ig = i0 + r;
      float v = (!diag || (jg < ig)) ? pa[r] * gpow[ig] : 0.f;
      Pq[ig * CHn + (jg ^ ((ig & 7) << 3))] = f2b(v);
    }
  };
  #pragma unroll
  for (int tj = 0; tj < 4; ++tj) if (tj < ntA) pw(accA[tj], tiA, tj, tj == ntA - 1);
  #pragma unroll
  for (int tj = 0; tj < 8; ++tj) if (tj < ntB) pw(accB[tj], tiB, tj, tj == ntB - 1);

  // zero tiles (read by the scan but zero by causality): per-wave 3
  int zi[3], zj[3];
  if      (w == 0){ zi[0]=4; zj[0]=5; zi[1]=4; zj[1]=6; zi[2]=4; zj[2]=7; }
  else if (w == 1){ zi[0]=5; zj[0]=6; zi[1]=5; zj[1]=7; zi[2]=0; zj[2]=1; }
  else if (w == 2){ zi[0]=6; zj[0]=7; zi[1]=0; zj[1]=2; zi[2]=0; zj[2]=3; }
  else            { zi[0]=1; zj[0]=2; zi[1]=1; zj[1]=3; zi[2]=2; zj[2]=3; }
  #pragma unroll
  for (int z = 0; z < 3; ++z){
    int jg = zj[z] * 16 + (lane & 15);
    int i0 = zi[z] * 16 + ((lane >> 4) << 2);
    #pragma unroll
    for (int r = 0; r < 4; ++r){
      int ig = i0 + r;
      Pq[ig * CHn + (jg ^ ((ig & 7) << 3))] = 0;
    }
  }
}

// ---------------- Kernel 3: scan (round-12 lattn_main, verbatim) ----------------
__global__ __launch_bounds__(512, 1) void lattn_main(
    const unsigned short* __restrict__ QR,
    const unsigned short* __restrict__ Pt,
    const float* __restrict__ V,
    const float* __restrict__ S_prev,
    const float* __restrict__ gammap,
    float* __restrict__ Out,
    float* __restrict__ Sfin)
{
  __shared__ __align__(16) unsigned short SbTs[16 * 512];
  __shared__ __align__(16) unsigned short VTs[2][16 * 128];
  __shared__ float gpow[129], gpinv[129];

  const int tid  = threadIdx.x;
  const int w    = tid >> 6;
  const int lane = tid & 63;
  const int bh   = blockIdx.x & 31;
  const int dch  = blockIdx.x >> 5;
  const int d0   = dch * 16;
  const float g  = gammap[0];

  const unsigned short* QRbh = QR + (size_t)bh * Tn * Nn;
  const unsigned short* Ptbh = Pt + (size_t)bh * NCH * (CHn * CHn);
  const float* Vbh = V + (size_t)bh * Tn * Dn;

  if (tid < 129){
    gpow[tid]  = powf(g,  (float)tid);
    gpinv[tid] = powf(g, -(float)tid);
  }

  const int snt = (w < 4) ? 2 : 6;
  const int sb  = (w < 4) ? w * 2 : 8 + (w - 4) * 6;
  f32x4 st[6];
  #pragma unroll
  for (int j = 0; j < 6; ++j) if (j < snt){
    int n = (sb + j) * 16 + (lane & 15);
    st[j] = *reinterpret_cast<const f32x4*>(
        S_prev + (size_t)bh * Nn * Dn + (size_t)n * Dn + d0 + ((lane >> 4) << 2));
  }
  __syncthreads();
  const float g128 = gpow[128];

  #pragma unroll
  for (int j = 0; j < 6; ++j) if (j < snt){
    int n  = (sb + j) * 16 + (lane & 15);
    int dl = (lane >> 4) << 2;
    #pragma unroll
    for (int r = 0; r < 4; ++r){
      int d = dl + r;
      SbTs[d * 512 + (n ^ ((d & 7) << 3))] = f2b(st[j][r]);
    }
  }
  {
    int dtv = tid >> 2, dp0 = (tid & 3) << 2;
    f32x4 v4 = *reinterpret_cast<const f32x4*>(Vbh + (size_t)dtv * Dn + d0 + dp0);
    float sc = gpinv[dtv];
    #pragma unroll
    for (int r = 0; r < 4; ++r){
      int d = dp0 + r;
      VTs[0][d * 128 + (dtv ^ ((d & 7) << 3))] = f2b(v4[r] * sc);
    }
  }
  __syncthreads();

  for (int c = 0; c < NCH; ++c){
    const int t0 = c * CHn;
    const int vb = c & 1;
    const bool pf = (c + 1 < NCH);
    const unsigned short* Qc = QRbh + (size_t)t0 * Nn;

    f32x4 va4 = {0.f, 0.f, 0.f, 0.f};
    const int dtv_ = tid >> 2, dp0_ = (tid & 3) << 2;
    if (pf)
      va4 = *reinterpret_cast<const f32x4*>(Vbh + (size_t)(t0 + CHn + dtv_) * Dn + d0 + dp0_);

    if (w < 4){
      const int it0 = w, it1 = w + 4;
      f32x4 o0 = {0.f,0.f,0.f,0.f}, o1 = o0;
      for (int kb = 0; kb < 16; ++kb){
        int k0 = kb * 32;
        short8 fs = ldfrag(SbTs, 0, k0, 512, lane);
        short8 fa = gfrag(Qc, it0 * 16, k0, lane);
        short8 fb = gfrag(Qc, it1 * 16, k0, lane);
        o0 = MFMA16(fs, fa, o0);
        o1 = MFMA16(fs, fb, o1);
      }
      float g0 = gpow[it0 * 16 + (lane & 15)];
      float g1 = gpow[it1 * 16 + (lane & 15)];
      #pragma unroll
      for (int r = 0; r < 4; ++r){ o0[r] *= g0; o1[r] *= g1; }
      const unsigned short* Pq = Ptbh + (size_t)c * (CHn * CHn);
      #pragma unroll
      for (int ks = 0; ks < 4; ++ks){
        short8 av = ldfrag(VTs[vb], 0, ks * 32, 128, lane);
        if (ks < 2){
          short8 b0 = ldfrag(Pq, it0 * 16, ks * 32, CHn, lane);
          o0 = MFMA16(av, b0, o0);
        }
        short8 b1 = ldfrag(Pq, it1 * 16, ks * 32, CHn, lane);
        o1 = MFMA16(av, b1, o1);
      }
      int ti0 = t0 + it0 * 16 + (lane & 15);
      int ti1 = t0 + it1 * 16 + (lane & 15);
      *reinterpret_cast<f32x4*>(
          Out + (size_t)bh * Tn * Dn + (size_t)ti0 * Dn + d0 + ((lane >> 4) << 2)) = o0;
      *reinterpret_cast<f32x4*>(
          Out + (size_t)bh * Tn * Dn + (size_t)ti1 * Dn + d0 + ((lane >> 4) << 2)) = o1;
    }
    #pragma unroll
    for (int ks = 0; ks < 4; ++ks){
      short8 av = ldfrag(VTs[vb], 0, ks * 32, 128, lane);
      #pragma unroll
      for (int j = 0; j < 6; ++j) if (j < snt){
        int n = (sb + j) * 16 + (lane & 15);
        const unsigned short* col = Qc + (size_t)(ks * 32 + ((lane >> 4) << 3)) * Nn + n;
        short8 bn;
        #pragma unroll
        for (int e = 0; e < 8; ++e) bn[e] = (short)col[(size_t)e * Nn];
        st[j] = MFMA16(av, bn, st[j]);
      }
    }
    #pragma unroll
    for (int j = 0; j < 6; ++j) if (j < snt)
      #pragma unroll
      for (int r = 0; r < 4; ++r) st[j][r] *= g128;
    __syncthreads();

    #pragma unroll
    for (int j = 0; j < 6; ++j) if (j < snt){
      int n  = (sb + j) * 16 + (lane & 15);
      int dl = (lane >> 4) << 2;
      #pragma unroll
      for (int r = 0; r < 4; ++r){
        int d = dl + r;
        SbTs[d * 512 + (n ^ ((d & 7) << 3))] = f2b(st[j][r]);
      }
    }
    if (pf){
      float sc = gpinv[dtv_];
      #pragma unroll
      for (int r = 0; r < 4; ++r){
        int d = dp0_ + r;
        VTs[vb ^ 1][d * 128 + (dtv_ ^ ((d & 7) << 3))] = f2b(va4[r] * sc);
      }
    }
    __syncthreads();
  }

  #pragma unroll
  for (int j = 0; j < 6; ++j) if (j < snt){
    int n = (sb + j) * 16 + (lane & 15);
    *reinterpret_cast<f32x4*>(
        Sfin + (size_t)bh * Nn * Dn + (size_t)n * Dn + d0 + ((lane >> 4) << 2)) = st[j];
  }
}

extern "C" void kernel_launch(void* const* d_in, const int* in_sizes, int n_in,
                              void* d_out, int out_size, void* d_ws, size_t ws_size,
                              hipStream_t stream){
  const float* Q      = (const float*)d_in[0];
  const float* V      = (const float*)d_in[1];
  const float* S_prev = (const float*)d_in[2];
  const float* freqs  = (const float*)d_in[3];
  const float* gamma  = (const float*)d_in[4];
  float* Out  = (float*)d_out;
  float* Sfin = Out + (size_t)BHn * Tn * Dn;

  unsigned short* QR = (unsigned short*)d_ws;                 // 64 MiB bf16
  unsigned short* Pt = QR + (size_t)BHn * Tn * Nn;            // +16 MiB P~ images

  rope_k<<<2048, 256, 0, stream>>>(Q, freqs, QR);
  pd_k<<<512, 256, 0, stream>>>(QR, gamma, Pt);
  lattn_main<<<256, 512, 0, stream>>>(QR, Pt, V, S_prev, gamma, Out, Sfin);
}